// Round 4
// baseline (481.819 us; speedup 1.0000x reference)
//
#include <hip/hip_runtime.h>

// Problem: B=8, Lq=Lk=1024, D=1024, H=8, dh=128.
// out0: (B,Lq,D) fp32 ; out1: similarity (H*B, Lq, Lk) fp32 (concatenated in d_out).
// Pipeline: [qkv proj bf16] -> [V transpose] -> [fused logits+softmax+PV]

#define TB 256
#define LDST 56  // LDS row stride (elems) for 32-wide bf16 tiles

typedef __attribute__((ext_vector_type(8))) short short8;
typedef __attribute__((ext_vector_type(4))) float f32x4;
typedef unsigned short u16;

__device__ __forceinline__ u16 f2bf(float f) {
  union { float f; unsigned u; } v; v.f = f;
  unsigned r = v.u + 0x7fffu + ((v.u >> 16) & 1u);  // round-to-nearest-even
  return (u16)(r >> 16);
}

// ---------------- Kernel 1: QKV projections  y = x @ W^T  (NT GEMM, fp32 in, bf16 out) ----------------
__global__ __launch_bounds__(TB) void qkv_gemm(
    const float* __restrict__ query, const float* __restrict__ keys,
    const float* __restrict__ Wq, const float* __restrict__ Wk, const float* __restrict__ Wv,
    u16* __restrict__ Qb, u16* __restrict__ Kb, u16* __restrict__ Vb) {
  __shared__ u16 As[128 * LDST];
  __shared__ u16 Bs[128 * LDST];
  const int z = blockIdx.z;
  const float* __restrict__ x = (z == 0) ? query : keys;
  const float* __restrict__ W = (z == 0) ? Wq : (z == 1) ? Wk : Wv;
  u16* __restrict__ dst = (z == 0) ? Qb : (z == 1) ? Kb : Vb;

  const int t = threadIdx.x;
  const int lane = t & 63, wid = t >> 6;
  const int wr = wid >> 1, wc = wid & 1;
  const int fr = lane & 15, ko = (lane >> 4) * 8;
  const int m0 = blockIdx.x * 128, n0 = blockIdx.y * 128;

  f32x4 acc[4][4] = {};

  for (int k0 = 0; k0 < 1024; k0 += 32) {
#pragma unroll
    for (int it = 0; it < 4; ++it) {
      int j = it * 256 + t;
      int row = j >> 3, c4 = (j & 7) * 4;
      float4 va = *(const float4*)&x[(size_t)(m0 + row) * 1024 + k0 + c4];
      float4 vb = *(const float4*)&W[(size_t)(n0 + row) * 1024 + k0 + c4];
      *(ushort4*)&As[row * LDST + c4] = make_ushort4(f2bf(va.x), f2bf(va.y), f2bf(va.z), f2bf(va.w));
      *(ushort4*)&Bs[row * LDST + c4] = make_ushort4(f2bf(vb.x), f2bf(vb.y), f2bf(vb.z), f2bf(vb.w));
    }
    __syncthreads();
    short8 a[4], bfrag[4];
#pragma unroll
    for (int i = 0; i < 4; ++i) a[i] = *(const short8*)&As[(wr * 64 + i * 16 + fr) * LDST + ko];
#pragma unroll
    for (int j = 0; j < 4; ++j) bfrag[j] = *(const short8*)&Bs[(wc * 64 + j * 16 + fr) * LDST + ko];
#pragma unroll
    for (int i = 0; i < 4; ++i)
#pragma unroll
      for (int j = 0; j < 4; ++j)
        acc[i][j] = __builtin_amdgcn_mfma_f32_16x16x32_bf16(a[i], bfrag[j], acc[i][j], 0, 0, 0);
    __syncthreads();
  }

  const int h = blockIdx.y;
#pragma unroll
  for (int i = 0; i < 4; ++i)
#pragma unroll
    for (int j = 0; j < 4; ++j)
#pragma unroll
      for (int r = 0; r < 4; ++r) {
        int m = m0 + wr * 64 + i * 16 + (lane >> 4) * 4 + r;
        int d = wc * 64 + j * 16 + fr;
        int b_ = m >> 10, q = m & 1023;
        dst[(((size_t)(b_ * 8 + h)) * 1024 + q) * 128 + d] = f2bf(acc[i][j][r]);
      }
}

// ---------------- Kernel 2: V transpose  (b,h,k,d) -> (b,h,d,k) ----------------
__global__ __launch_bounds__(TB) void vtrans(const u16* __restrict__ Vb, u16* __restrict__ Vt) {
  __shared__ u16 tile[32][33];
  const int bh = blockIdx.z;
  const u16* __restrict__ src = Vb + (size_t)bh * 1024 * 128;
  u16* __restrict__ dst = Vt + (size_t)bh * 128 * 1024;
  const int k0 = blockIdx.x * 32, d0 = blockIdx.y * 32;
  const int t = threadIdx.x;
#pragma unroll
  for (int i = 0; i < 4; ++i) {
    int j = i * 256 + t;
    int r = j >> 5, c = j & 31;
    tile[r][c] = src[(size_t)(k0 + r) * 128 + d0 + c];
  }
  __syncthreads();
#pragma unroll
  for (int i = 0; i < 4; ++i) {
    int j = i * 256 + t;
    int r = j >> 5, c = j & 31;
    dst[(size_t)(d0 + r) * 1024 + k0 + c] = tile[c][r];
  }
}

// ---------------- Kernel 3: fused logits + softmax + PV ----------------
// Block = (qb: 32 q-rows, bh). 4 waves. Wave w owns columns
// {(pt>>3)*512 + w*128 + (pt&7)*16 + fr : pt=0..15} (two 128-wide strips, one per 512-chunk).
// S row (1024) held in registers: acc[2][16] f32x4 per lane.
// PV runs in two 512-col chunks through a 32 KB LDS P-buffer for occupancy.
__global__ __launch_bounds__(TB, 3) void fused_attn(
    const u16* __restrict__ Qb, const u16* __restrict__ Kb, const u16* __restrict__ Vt,
    const int* __restrict__ mask, const float* __restrict__ rel,
    float* __restrict__ sim, float* __restrict__ out) {
  __shared__ u16 Pl[32 * 512];     // normalized P chunk, bf16, XOR-swizzled
  __shared__ float redm[4][32];
  __shared__ float reds[4][32];

  // Bijective XCD swizzle: id&7 = XCD slot; all 32 q-blocks of a bh land on one XCD.
  const int id = blockIdx.x + 32 * blockIdx.y;
  const int jj = id >> 3;
  const int z = (id & 7) + 8 * (jj >> 5);  // bh index, z mod 8 == XCD slot
  const int qb = jj & 31;
  const int h = z >> 3, b = z & 7;

  const int t = threadIdx.x;
  const int lane = t & 63, w = t >> 6;
  const int fr = lane & 15, g = lane >> 4;
  const int ko = g * 8;

  const size_t bh_off = (size_t)(b * 8 + h) * 1024 * 128;
  const u16* __restrict__ Qp = Qb + bh_off + (size_t)(qb * 32) * 128;
  const u16* __restrict__ Kp = Kb + bh_off;
  const u16* __restrict__ Vp = Vt + bh_off;   // (d,k) layout

  // ---- Phase 1: S = Q.K^T ----
  short8 qf[2][4];
#pragma unroll
  for (int m = 0; m < 2; ++m)
#pragma unroll
    for (int ks = 0; ks < 4; ++ks)
      qf[m][ks] = *(const short8*)&Qp[(size_t)(m * 16 + fr) * 128 + ks * 32 + ko];

  f32x4 acc[2][16] = {};
#pragma unroll
  for (int pt = 0; pt < 16; ++pt) {
    const int col0 = (pt >> 3) * 512 + w * 128 + (pt & 7) * 16;
    const u16* kb = Kp + (size_t)(col0 + fr) * 128 + ko;
#pragma unroll
    for (int ks = 0; ks < 4; ++ks) {
      short8 kf = *(const short8*)&kb[ks * 32];
      acc[0][pt] = __builtin_amdgcn_mfma_f32_16x16x32_bf16(qf[0][ks], kf, acc[0][pt], 0, 0, 0);
      acc[1][pt] = __builtin_amdgcn_mfma_f32_16x16x32_bf16(qf[1][ks], kf, acc[1][pt], 0, 0, 0);
    }
  }

  // ---- Phase 2: rel + mask, in-register ----
  const float scale = 0.03125f;  // 1/sqrt(1024)
#pragma unroll
  for (int m = 0; m < 2; ++m)
#pragma unroll
    for (int r = 0; r < 4; ++r) {
      const int qrow = qb * 32 + m * 16 + g * 4 + r;
      const size_t rbase = ((size_t)b * 1024 + qrow) * 1024 + fr;
#pragma unroll
      for (int pt = 0; pt < 16; ++pt) {
        const int col0 = (pt >> 3) * 512 + w * 128 + (pt & 7) * 16;
        size_t idx = rbase + col0;
        float v = (acc[m][pt][r] + rel[idx]) * scale;
        acc[m][pt][r] = (mask[idx] > 0) ? v : -1e9f;
      }
    }

  // ---- Phase 3: row max ----
  float mloc[2][4];
#pragma unroll
  for (int m = 0; m < 2; ++m)
#pragma unroll
    for (int r = 0; r < 4; ++r) {
      float mx = acc[m][0][r];
#pragma unroll
      for (int pt = 1; pt < 16; ++pt) mx = fmaxf(mx, acc[m][pt][r]);
      mx = fmaxf(mx, __shfl_xor(mx, 1));
      mx = fmaxf(mx, __shfl_xor(mx, 2));
      mx = fmaxf(mx, __shfl_xor(mx, 4));
      mx = fmaxf(mx, __shfl_xor(mx, 8));
      mloc[m][r] = mx;
    }
  if (fr == 0) {
#pragma unroll
    for (int m = 0; m < 2; ++m)
#pragma unroll
      for (int r = 0; r < 4; ++r) redm[w][m * 16 + g * 4 + r] = mloc[m][r];
  }
  __syncthreads();

  // ---- Phase 4: exp + row sum ----
  float sv[2][4];
#pragma unroll
  for (int m = 0; m < 2; ++m)
#pragma unroll
    for (int r = 0; r < 4; ++r) {
      const int rl = m * 16 + g * 4 + r;
      float mx = fmaxf(fmaxf(redm[0][rl], redm[1][rl]), fmaxf(redm[2][rl], redm[3][rl]));
      float s = 0.f;
#pragma unroll
      for (int pt = 0; pt < 16; ++pt) {
        float e = __expf(acc[m][pt][r] - mx);
        acc[m][pt][r] = e;
        s += e;
      }
      s += __shfl_xor(s, 1);
      s += __shfl_xor(s, 2);
      s += __shfl_xor(s, 4);
      s += __shfl_xor(s, 8);
      sv[m][r] = s;
    }
  if (fr == 0) {
#pragma unroll
    for (int m = 0; m < 2; ++m)
#pragma unroll
      for (int r = 0; r < 4; ++r) reds[w][m * 16 + g * 4 + r] = sv[m][r];
  }
  __syncthreads();

  // ---- Phase 5a: normalize in-register + write sim (all columns) ----
  const size_t sim_base = ((size_t)(h * 8 + b) * 1024 + qb * 32) * 1024;
#pragma unroll
  for (int m = 0; m < 2; ++m)
#pragma unroll
    for (int r = 0; r < 4; ++r) {
      const int rl = m * 16 + g * 4 + r;
      float s = reds[0][rl] + reds[1][rl] + reds[2][rl] + reds[3][rl];
      float iv = 1.0f / s;
#pragma unroll
      for (int pt = 0; pt < 16; ++pt) {
        const int col = (pt >> 3) * 512 + w * 128 + (pt & 7) * 16 + fr;
        float p = acc[m][pt][r] * iv;
        acc[m][pt][r] = p;
        sim[sim_base + (size_t)rl * 1024 + col] = p;
      }
    }

  // ---- Phase 5b/6: two 512-col chunks: stash P in LDS (swizzled), PV-accumulate ----
  f32x4 oacc[2][2] = {};
  const int d0 = w * 32;
#pragma unroll
  for (int cb = 0; cb < 2; ++cb) {
#pragma unroll
    for (int m = 0; m < 2; ++m)
#pragma unroll
      for (int r = 0; r < 4; ++r) {
        const int rl = m * 16 + g * 4 + r;
        const int swz = (rl & 15) << 3;  // element XOR (16B granularity)
#pragma unroll
        for (int p8 = 0; p8 < 8; ++p8) {
          const int colc = w * 128 + p8 * 16 + fr;   // col within chunk
          Pl[rl * 512 + (colc ^ swz)] = f2bf(acc[m][cb * 8 + p8][r]);
        }
      }
    __syncthreads();
#pragma unroll
    for (int ksl = 0; ksl < 16; ++ksl) {
      short8 pa[2], vb2[2];
#pragma unroll
      for (int m = 0; m < 2; ++m) {
        const int prow = m * 16 + fr;
        pa[m] = *(const short8*)&Pl[prow * 512 + ((ksl * 32 + ko) ^ ((prow & 15) << 3))];
      }
#pragma unroll
      for (int dt = 0; dt < 2; ++dt)
        vb2[dt] = *(const short8*)&Vp[(size_t)(d0 + dt * 16 + fr) * 1024 + cb * 512 + ksl * 32 + ko];
#pragma unroll
      for (int m = 0; m < 2; ++m)
#pragma unroll
        for (int dt = 0; dt < 2; ++dt)
          oacc[m][dt] = __builtin_amdgcn_mfma_f32_16x16x32_bf16(pa[m], vb2[dt], oacc[m][dt], 0, 0, 0);
    }
    __syncthreads();
  }

#pragma unroll
  for (int m = 0; m < 2; ++m)
#pragma unroll
    for (int dt = 0; dt < 2; ++dt)
#pragma unroll
      for (int r = 0; r < 4; ++r) {
        const int q = qb * 32 + m * 16 + g * 4 + r;
        const int d = d0 + dt * 16 + fr;
        out[((size_t)b * 1024 + q) * 1024 + h * 128 + d] = oacc[m][dt][r];
      }
}

extern "C" void kernel_launch(void* const* d_in, const int* in_sizes, int n_in,
                              void* d_out, int out_size, void* d_ws, size_t ws_size,
                              hipStream_t stream) {
  (void)in_sizes; (void)n_in; (void)out_size; (void)ws_size;
  const float* query = (const float*)d_in[0];
  const float* keys  = (const float*)d_in[1];
  const int*   mask  = (const int*)d_in[2];
  const float* rel   = (const float*)d_in[3];
  const float* Wq    = (const float*)d_in[4];
  const float* Wk    = (const float*)d_in[5];
  const float* Wv    = (const float*)d_in[6];

  float* out = (float*)d_out;                       // (B,Lq,D) = 8M floats
  float* sim = out + (size_t)8 * 1024 * 1024;       // (H*B,Lq,Lk) = 64M floats

  const size_t NE = (size_t)8 * 8 * 1024 * 128;     // 8.39M bf16 elems per buffer
  u16* Qb = (u16*)d_ws;                             // ws usage: 64 MB total
  u16* Kb = Qb + NE;
  u16* Vb = Kb + NE;
  u16* Vt = Vb + NE;

  qkv_gemm<<<dim3(64, 8, 3), TB, 0, stream>>>(query, keys, Wq, Wk, Wv, Qb, Kb, Vb);
  vtrans<<<dim3(32, 4, 64), TB, 0, stream>>>(Vb, Vt);
  fused_attn<<<dim3(32, 64), TB, 0, stream>>>(Qb, Kb, Vt, mask, rel, sim, out);
}

// Round 5
// 438.652 us; speedup vs baseline: 1.0984x; 1.0984x over previous
//
#include <hip/hip_runtime.h>

// Problem: B=8, Lq=Lk=1024, D=1024, H=8, dh=128.
// out0: (B,Lq,D) fp32 ; out1: similarity (H*B, Lq, Lk) fp32 (concatenated in d_out).
// Pipeline: [qkv proj bf16] -> [V transpose] -> [fused logits+softmax+PV]

#define TB 256
#define LDST 56  // LDS row stride (elems) for 32-wide bf16 tiles

typedef __attribute__((ext_vector_type(8))) short short8;
typedef __attribute__((ext_vector_type(4))) float f32x4;
typedef unsigned short u16;

__device__ __forceinline__ u16 f2bf(float f) {
  union { float f; unsigned u; } v; v.f = f;
  unsigned r = v.u + 0x7fffu + ((v.u >> 16) & 1u);  // round-to-nearest-even
  return (u16)(r >> 16);
}

// ---------------- Kernel 1: QKV projections  y = x @ W^T  (NT GEMM, fp32 in, bf16 out) ----------------
__global__ __launch_bounds__(TB) void qkv_gemm(
    const float* __restrict__ query, const float* __restrict__ keys,
    const float* __restrict__ Wq, const float* __restrict__ Wk, const float* __restrict__ Wv,
    u16* __restrict__ Qb, u16* __restrict__ Kb, u16* __restrict__ Vb) {
  __shared__ u16 As[128 * LDST];
  __shared__ u16 Bs[128 * LDST];
  const int z = blockIdx.z;
  const float* __restrict__ x = (z == 0) ? query : keys;
  const float* __restrict__ W = (z == 0) ? Wq : (z == 1) ? Wk : Wv;
  u16* __restrict__ dst = (z == 0) ? Qb : (z == 1) ? Kb : Vb;

  const int t = threadIdx.x;
  const int lane = t & 63, wid = t >> 6;
  const int wr = wid >> 1, wc = wid & 1;
  const int fr = lane & 15, ko = (lane >> 4) * 8;
  const int m0 = blockIdx.x * 128, n0 = blockIdx.y * 128;

  f32x4 acc[4][4] = {};

  for (int k0 = 0; k0 < 1024; k0 += 32) {
#pragma unroll
    for (int it = 0; it < 4; ++it) {
      int j = it * 256 + t;
      int row = j >> 3, c4 = (j & 7) * 4;
      float4 va = *(const float4*)&x[(size_t)(m0 + row) * 1024 + k0 + c4];
      float4 vb = *(const float4*)&W[(size_t)(n0 + row) * 1024 + k0 + c4];
      *(ushort4*)&As[row * LDST + c4] = make_ushort4(f2bf(va.x), f2bf(va.y), f2bf(va.z), f2bf(va.w));
      *(ushort4*)&Bs[row * LDST + c4] = make_ushort4(f2bf(vb.x), f2bf(vb.y), f2bf(vb.z), f2bf(vb.w));
    }
    __syncthreads();
    short8 a[4], bfrag[4];
#pragma unroll
    for (int i = 0; i < 4; ++i) a[i] = *(const short8*)&As[(wr * 64 + i * 16 + fr) * LDST + ko];
#pragma unroll
    for (int j = 0; j < 4; ++j) bfrag[j] = *(const short8*)&Bs[(wc * 64 + j * 16 + fr) * LDST + ko];
#pragma unroll
    for (int i = 0; i < 4; ++i)
#pragma unroll
      for (int j = 0; j < 4; ++j)
        acc[i][j] = __builtin_amdgcn_mfma_f32_16x16x32_bf16(a[i], bfrag[j], acc[i][j], 0, 0, 0);
    __syncthreads();
  }

  const int h = blockIdx.y;
#pragma unroll
  for (int i = 0; i < 4; ++i)
#pragma unroll
    for (int j = 0; j < 4; ++j)
#pragma unroll
      for (int r = 0; r < 4; ++r) {
        int m = m0 + wr * 64 + i * 16 + (lane >> 4) * 4 + r;
        int d = wc * 64 + j * 16 + fr;
        int b_ = m >> 10, q = m & 1023;
        dst[(((size_t)(b_ * 8 + h)) * 1024 + q) * 128 + d] = f2bf(acc[i][j][r]);
      }
}

// ---------------- Kernel 2: V transpose  (b,h,k,d) -> (b,h,d,k) ----------------
__global__ __launch_bounds__(TB) void vtrans(const u16* __restrict__ Vb, u16* __restrict__ Vt) {
  __shared__ u16 tile[32][33];
  const int bh = blockIdx.z;
  const u16* __restrict__ src = Vb + (size_t)bh * 1024 * 128;
  u16* __restrict__ dst = Vt + (size_t)bh * 128 * 1024;
  const int k0 = blockIdx.x * 32, d0 = blockIdx.y * 32;
  const int t = threadIdx.x;
#pragma unroll
  for (int i = 0; i < 4; ++i) {
    int j = i * 256 + t;
    int r = j >> 5, c = j & 31;
    tile[r][c] = src[(size_t)(k0 + r) * 128 + d0 + c];
  }
  __syncthreads();
#pragma unroll
  for (int i = 0; i < 4; ++i) {
    int j = i * 256 + t;
    int r = j >> 5, c = j & 31;
    dst[(size_t)(d0 + r) * 1024 + k0 + c] = tile[c][r];
  }
}

// ---------------- Kernel 3: fused logits + softmax + PV ----------------
// Block = (qb: 16 q-rows, bh). 4 waves; wave w owns columns [w*256, w*256+256).
// S row (1024) held in registers: acc[16] f32x4 per lane (64 VGPR live; no spill).
// Pl = 16 rows x 1024 cols bf16 (32 KB) -> 4 blocks/CU.
__global__ __launch_bounds__(TB) void fused_attn(
    const u16* __restrict__ Qb, const u16* __restrict__ Kb, const u16* __restrict__ Vt,
    const int* __restrict__ mask, const float* __restrict__ rel,
    float* __restrict__ sim, float* __restrict__ out) {
  __shared__ u16 Pl[16 * 1024];    // normalized P, bf16, XOR-swizzled
  __shared__ float redm[4][16];
  __shared__ float reds[4][16];

  // Bijective XCD decode: id&7 = XCD slot; all 64 q-blocks of a bh on one XCD.
  const int id = blockIdx.x;       // 4096 blocks
  const int xcd = id & 7, j = id >> 3;
  const int z = xcd + 8 * (j >> 6);   // bh
  const int qb = j & 63;              // 64 q-blocks of 16 rows
  const int h = z >> 3, b = z & 7;

  const int t = threadIdx.x;
  const int lane = t & 63, w = t >> 6;
  const int fr = lane & 15, g = lane >> 4;
  const int ko = g * 8;

  const size_t bh_off = (size_t)(b * 8 + h) * 1024 * 128;
  const u16* __restrict__ Qp = Qb + bh_off + (size_t)(qb * 16) * 128;
  const u16* __restrict__ Kp = Kb + bh_off;
  const u16* __restrict__ Vp = Vt + bh_off;   // (d,k) layout

  // ---- Phase 1: S = Q.K^T  (16 rows x 1024 cols; wave w -> cols w*256..w*256+255) ----
  short8 qf[4];
#pragma unroll
  for (int ks = 0; ks < 4; ++ks)
    qf[ks] = *(const short8*)&Qp[(size_t)fr * 128 + ks * 32 + ko];

  f32x4 acc[16] = {};
#pragma unroll
  for (int pt = 0; pt < 16; ++pt) {
    const u16* kb = Kp + (size_t)(w * 256 + pt * 16 + fr) * 128 + ko;
#pragma unroll
    for (int ks = 0; ks < 4; ++ks) {
      short8 kf = *(const short8*)&kb[ks * 32];
      acc[pt] = __builtin_amdgcn_mfma_f32_16x16x32_bf16(qf[ks], kf, acc[pt], 0, 0, 0);
    }
  }

  // ---- Phase 2: rel + mask, in-register ----
  const float scale = 0.03125f;  // 1/sqrt(1024)
#pragma unroll
  for (int r = 0; r < 4; ++r) {
    const int qrow = qb * 16 + g * 4 + r;
    const size_t rbase = ((size_t)b * 1024 + qrow) * 1024 + w * 256 + fr;
#pragma unroll
    for (int pt = 0; pt < 16; ++pt) {
      size_t idx = rbase + pt * 16;
      float v = (acc[pt][r] + rel[idx]) * scale;
      acc[pt][r] = (mask[idx] > 0) ? v : -1e9f;
    }
  }

  // ---- Phase 3: row max (16 local -> 16-lane shfl -> LDS cross-wave) ----
  float mloc[4];
#pragma unroll
  for (int r = 0; r < 4; ++r) {
    float mx = acc[0][r];
#pragma unroll
    for (int pt = 1; pt < 16; ++pt) mx = fmaxf(mx, acc[pt][r]);
    mx = fmaxf(mx, __shfl_xor(mx, 1));
    mx = fmaxf(mx, __shfl_xor(mx, 2));
    mx = fmaxf(mx, __shfl_xor(mx, 4));
    mx = fmaxf(mx, __shfl_xor(mx, 8));
    mloc[r] = mx;
  }
  if (fr == 0) {
#pragma unroll
    for (int r = 0; r < 4; ++r) redm[w][g * 4 + r] = mloc[r];
  }
  __syncthreads();

  // ---- Phase 4: exp + row sum ----
  float sv[4];
#pragma unroll
  for (int r = 0; r < 4; ++r) {
    const int rl = g * 4 + r;
    float mx = fmaxf(fmaxf(redm[0][rl], redm[1][rl]), fmaxf(redm[2][rl], redm[3][rl]));
    float s = 0.f;
#pragma unroll
    for (int pt = 0; pt < 16; ++pt) {
      float e = __expf(acc[pt][r] - mx);
      acc[pt][r] = e;
      s += e;
    }
    s += __shfl_xor(s, 1);
    s += __shfl_xor(s, 2);
    s += __shfl_xor(s, 4);
    s += __shfl_xor(s, 8);
    sv[r] = s;
  }
  if (fr == 0) {
#pragma unroll
    for (int r = 0; r < 4; ++r) reds[w][g * 4 + r] = sv[r];
  }
  __syncthreads();

  // ---- Phase 5: normalize; write sim (fp32) + P (bf16, swizzled LDS) ----
  const size_t sim_base = ((size_t)(h * 8 + b) * 1024 + qb * 16) * 1024;
#pragma unroll
  for (int r = 0; r < 4; ++r) {
    const int rl = g * 4 + r;
    float s = reds[0][rl] + reds[1][rl] + reds[2][rl] + reds[3][rl];
    float iv = 1.0f / s;
    const int swz = rl << 3;  // element XOR (16B granularity)
#pragma unroll
    for (int pt = 0; pt < 16; ++pt) {
      const int col = w * 256 + pt * 16 + fr;
      float p = acc[pt][r] * iv;
      sim[sim_base + (size_t)rl * 1024 + col] = p;
      Pl[rl * 1024 + (col ^ swz)] = f2bf(p);
    }
  }
  __syncthreads();

  // ---- Phase 6: out(16x128) = P(16x1024) @ V^T  (Vt is (d,k), k-contiguous) ----
  // wave w -> d-tiles {2w, 2w+1}
  f32x4 oacc[2] = {};
  const int d0 = w * 32;
#pragma unroll
  for (int ksl = 0; ksl < 32; ++ksl) {
    const int prow = fr;
    short8 pa = *(const short8*)&Pl[prow * 1024 + ((ksl * 32 + ko) ^ (prow << 3))];
    short8 vb2[2];
#pragma unroll
    for (int dt = 0; dt < 2; ++dt)
      vb2[dt] = *(const short8*)&Vp[(size_t)(d0 + dt * 16 + fr) * 1024 + ksl * 32 + ko];
#pragma unroll
    for (int dt = 0; dt < 2; ++dt)
      oacc[dt] = __builtin_amdgcn_mfma_f32_16x16x32_bf16(pa, vb2[dt], oacc[dt], 0, 0, 0);
  }

#pragma unroll
  for (int dt = 0; dt < 2; ++dt)
#pragma unroll
    for (int r = 0; r < 4; ++r) {
      const int q = qb * 16 + g * 4 + r;
      const int d = d0 + dt * 16 + fr;
      out[((size_t)b * 1024 + q) * 1024 + h * 128 + d] = oacc[dt][r];
    }
}

extern "C" void kernel_launch(void* const* d_in, const int* in_sizes, int n_in,
                              void* d_out, int out_size, void* d_ws, size_t ws_size,
                              hipStream_t stream) {
  (void)in_sizes; (void)n_in; (void)out_size; (void)ws_size;
  const float* query = (const float*)d_in[0];
  const float* keys  = (const float*)d_in[1];
  const int*   mask  = (const int*)d_in[2];
  const float* rel   = (const float*)d_in[3];
  const float* Wq    = (const float*)d_in[4];
  const float* Wk    = (const float*)d_in[5];
  const float* Wv    = (const float*)d_in[6];

  float* out = (float*)d_out;                       // (B,Lq,D) = 8M floats
  float* sim = out + (size_t)8 * 1024 * 1024;       // (H*B,Lq,Lk) = 64M floats

  const size_t NE = (size_t)8 * 8 * 1024 * 128;     // 8.39M bf16 elems per buffer
  u16* Qb = (u16*)d_ws;                             // ws usage: 64 MB total
  u16* Kb = Qb + NE;
  u16* Vb = Kb + NE;
  u16* Vt = Vb + NE;

  qkv_gemm<<<dim3(64, 8, 3), TB, 0, stream>>>(query, keys, Wq, Wk, Wv, Qb, Kb, Vb);
  vtrans<<<dim3(32, 4, 64), TB, 0, stream>>>(Vb, Vt);
  fused_attn<<<dim3(4096), TB, 0, stream>>>(Qb, Kb, Vt, mask, rel, sim, out);
}

// Round 6
// 437.516 us; speedup vs baseline: 1.1013x; 1.0026x over previous
//
#include <hip/hip_runtime.h>

// Problem: B=8, Lq=Lk=1024, D=1024, H=8, dh=128.
// out0: (B,Lq,D) fp32 ; out1: similarity (H*B, Lq, Lk) fp32 (concatenated in d_out).
// Pipeline: [qkv proj bf16] -> [V transpose] -> [fused logits+softmax+PV]

#define TB 256
#define LDST 56  // LDS row stride (elems) for 32-wide bf16 tiles

typedef __attribute__((ext_vector_type(8))) short short8;
typedef __attribute__((ext_vector_type(4))) float f32x4;
typedef unsigned short u16;

__device__ __forceinline__ u16 f2bf(float f) {
  union { float f; unsigned u; } v; v.f = f;
  unsigned r = v.u + 0x7fffu + ((v.u >> 16) & 1u);  // round-to-nearest-even
  return (u16)(r >> 16);
}

// ---------------- Kernel 1: QKV projections  y = x @ W^T  (NT GEMM, fp32 in, bf16 out) ----------------
__global__ __launch_bounds__(TB) void qkv_gemm(
    const float* __restrict__ query, const float* __restrict__ keys,
    const float* __restrict__ Wq, const float* __restrict__ Wk, const float* __restrict__ Wv,
    u16* __restrict__ Qb, u16* __restrict__ Kb, u16* __restrict__ Vb) {
  __shared__ u16 As[128 * LDST];
  __shared__ u16 Bs[128 * LDST];
  const int z = blockIdx.z;
  const float* __restrict__ x = (z == 0) ? query : keys;
  const float* __restrict__ W = (z == 0) ? Wq : (z == 1) ? Wk : Wv;
  u16* __restrict__ dst = (z == 0) ? Qb : (z == 1) ? Kb : Vb;

  const int t = threadIdx.x;
  const int lane = t & 63, wid = t >> 6;
  const int wr = wid >> 1, wc = wid & 1;
  const int fr = lane & 15, ko = (lane >> 4) * 8;
  const int m0 = blockIdx.x * 128, n0 = blockIdx.y * 128;

  f32x4 acc[4][4] = {};

  for (int k0 = 0; k0 < 1024; k0 += 32) {
#pragma unroll
    for (int it = 0; it < 4; ++it) {
      int j = it * 256 + t;
      int row = j >> 3, c4 = (j & 7) * 4;
      float4 va = *(const float4*)&x[(size_t)(m0 + row) * 1024 + k0 + c4];
      float4 vb = *(const float4*)&W[(size_t)(n0 + row) * 1024 + k0 + c4];
      *(ushort4*)&As[row * LDST + c4] = make_ushort4(f2bf(va.x), f2bf(va.y), f2bf(va.z), f2bf(va.w));
      *(ushort4*)&Bs[row * LDST + c4] = make_ushort4(f2bf(vb.x), f2bf(vb.y), f2bf(vb.z), f2bf(vb.w));
    }
    __syncthreads();
    short8 a[4], bfrag[4];
#pragma unroll
    for (int i = 0; i < 4; ++i) a[i] = *(const short8*)&As[(wr * 64 + i * 16 + fr) * LDST + ko];
#pragma unroll
    for (int j = 0; j < 4; ++j) bfrag[j] = *(const short8*)&Bs[(wc * 64 + j * 16 + fr) * LDST + ko];
#pragma unroll
    for (int i = 0; i < 4; ++i)
#pragma unroll
      for (int j = 0; j < 4; ++j)
        acc[i][j] = __builtin_amdgcn_mfma_f32_16x16x32_bf16(a[i], bfrag[j], acc[i][j], 0, 0, 0);
    __syncthreads();
  }

  const int h = blockIdx.y;
#pragma unroll
  for (int i = 0; i < 4; ++i)
#pragma unroll
    for (int j = 0; j < 4; ++j)
#pragma unroll
      for (int r = 0; r < 4; ++r) {
        int m = m0 + wr * 64 + i * 16 + (lane >> 4) * 4 + r;
        int d = wc * 64 + j * 16 + fr;
        int b_ = m >> 10, q = m & 1023;
        dst[(((size_t)(b_ * 8 + h)) * 1024 + q) * 128 + d] = f2bf(acc[i][j][r]);
      }
}

// ---------------- Kernel 2: V transpose  (b,h,k,d) -> (b,h,d,k) ----------------
__global__ __launch_bounds__(TB) void vtrans(const u16* __restrict__ Vb, u16* __restrict__ Vt) {
  __shared__ u16 tile[32][33];
  const int bh = blockIdx.z;
  const u16* __restrict__ src = Vb + (size_t)bh * 1024 * 128;
  u16* __restrict__ dst = Vt + (size_t)bh * 128 * 1024;
  const int k0 = blockIdx.x * 32, d0 = blockIdx.y * 32;
  const int t = threadIdx.x;
#pragma unroll
  for (int i = 0; i < 4; ++i) {
    int j = i * 256 + t;
    int r = j >> 5, c = j & 31;
    tile[r][c] = src[(size_t)(k0 + r) * 128 + d0 + c];
  }
  __syncthreads();
#pragma unroll
  for (int i = 0; i < 4; ++i) {
    int j = i * 256 + t;
    int r = j >> 5, c = j & 31;
    dst[(size_t)(d0 + r) * 1024 + k0 + c] = tile[c][r];
  }
}

// ---------------- Kernel 3: fused logits + softmax + PV ----------------
// Block = (qb: 32 q-rows, bh). 4 waves. Wave w owns columns
// {(pt>>3)*512 + w*128 + (pt&7)*16 + fr : pt=0..15} (two 128-wide strips, one per 512-chunk).
// S row (1024) in registers: acc[2][16] f32x4 per lane. PV in two 512-col chunks
// through a 32 KB LDS P-buffer. NO register cap: r4's (256,3) caused a spill
// (VGPR 84, +150 MB scratch traffic); natural allocation is ~128.
__global__ __launch_bounds__(TB) void fused_attn(
    const u16* __restrict__ Qb, const u16* __restrict__ Kb, const u16* __restrict__ Vt,
    const int* __restrict__ mask, const float* __restrict__ rel,
    float* __restrict__ sim, float* __restrict__ out) {
  __shared__ u16 Pl[32 * 512];     // normalized P chunk, bf16, XOR-swizzled
  __shared__ float redm[4][32];
  __shared__ float reds[4][32];

  // Bijective XCD swizzle: id&7 = XCD slot; all 32 q-blocks of a bh land on one XCD.
  const int id = blockIdx.x;       // 2048 blocks
  const int jj = id >> 3;
  const int z = (id & 7) + 8 * (jj >> 5);  // bh index
  const int qb = jj & 31;
  const int h = z >> 3, b = z & 7;

  const int t = threadIdx.x;
  const int lane = t & 63, w = t >> 6;
  const int fr = lane & 15, g = lane >> 4;
  const int ko = g * 8;

  const size_t bh_off = (size_t)(b * 8 + h) * 1024 * 128;
  const u16* __restrict__ Qp = Qb + bh_off + (size_t)(qb * 32) * 128;
  const u16* __restrict__ Kp = Kb + bh_off;
  const u16* __restrict__ Vp = Vt + bh_off;   // (d,k) layout

  // ---- Phase 1: S = Q.K^T ----
  short8 qf[2][4];
#pragma unroll
  for (int m = 0; m < 2; ++m)
#pragma unroll
    for (int ks = 0; ks < 4; ++ks)
      qf[m][ks] = *(const short8*)&Qp[(size_t)(m * 16 + fr) * 128 + ks * 32 + ko];

  f32x4 acc[2][16] = {};
#pragma unroll
  for (int pt = 0; pt < 16; ++pt) {
    const int col0 = (pt >> 3) * 512 + w * 128 + (pt & 7) * 16;
    const u16* kb = Kp + (size_t)(col0 + fr) * 128 + ko;
#pragma unroll
    for (int ks = 0; ks < 4; ++ks) {
      short8 kf = *(const short8*)&kb[ks * 32];
      acc[0][pt] = __builtin_amdgcn_mfma_f32_16x16x32_bf16(qf[0][ks], kf, acc[0][pt], 0, 0, 0);
      acc[1][pt] = __builtin_amdgcn_mfma_f32_16x16x32_bf16(qf[1][ks], kf, acc[1][pt], 0, 0, 0);
    }
  }

  // ---- Phase 2: rel + mask, in-register ----
  const float scale = 0.03125f;  // 1/sqrt(1024)
#pragma unroll
  for (int m = 0; m < 2; ++m)
#pragma unroll
    for (int r = 0; r < 4; ++r) {
      const int qrow = qb * 32 + m * 16 + g * 4 + r;
      const size_t rbase = ((size_t)b * 1024 + qrow) * 1024 + fr;
#pragma unroll
      for (int pt = 0; pt < 16; ++pt) {
        const int col0 = (pt >> 3) * 512 + w * 128 + (pt & 7) * 16;
        size_t idx = rbase + col0;
        float v = (acc[m][pt][r] + rel[idx]) * scale;
        acc[m][pt][r] = (mask[idx] > 0) ? v : -1e9f;
      }
    }

  // ---- Phase 3: row max ----
  float mloc[2][4];
#pragma unroll
  for (int m = 0; m < 2; ++m)
#pragma unroll
    for (int r = 0; r < 4; ++r) {
      float mx = acc[m][0][r];
#pragma unroll
      for (int pt = 1; pt < 16; ++pt) mx = fmaxf(mx, acc[m][pt][r]);
      mx = fmaxf(mx, __shfl_xor(mx, 1));
      mx = fmaxf(mx, __shfl_xor(mx, 2));
      mx = fmaxf(mx, __shfl_xor(mx, 4));
      mx = fmaxf(mx, __shfl_xor(mx, 8));
      mloc[m][r] = mx;
    }
  if (fr == 0) {
#pragma unroll
    for (int m = 0; m < 2; ++m)
#pragma unroll
      for (int r = 0; r < 4; ++r) redm[w][m * 16 + g * 4 + r] = mloc[m][r];
  }
  __syncthreads();

  // ---- Phase 4: exp + row sum ----
  float sv[2][4];
#pragma unroll
  for (int m = 0; m < 2; ++m)
#pragma unroll
    for (int r = 0; r < 4; ++r) {
      const int rl = m * 16 + g * 4 + r;
      float mx = fmaxf(fmaxf(redm[0][rl], redm[1][rl]), fmaxf(redm[2][rl], redm[3][rl]));
      float s = 0.f;
#pragma unroll
      for (int pt = 0; pt < 16; ++pt) {
        float e = __expf(acc[m][pt][r] - mx);
        acc[m][pt][r] = e;
        s += e;
      }
      s += __shfl_xor(s, 1);
      s += __shfl_xor(s, 2);
      s += __shfl_xor(s, 4);
      s += __shfl_xor(s, 8);
      sv[m][r] = s;
    }
  if (fr == 0) {
#pragma unroll
    for (int m = 0; m < 2; ++m)
#pragma unroll
      for (int r = 0; r < 4; ++r) reds[w][m * 16 + g * 4 + r] = sv[m][r];
  }
  __syncthreads();

  // ---- Phase 5a: normalize in-register + write sim (all columns) ----
  const size_t sim_base = ((size_t)(h * 8 + b) * 1024 + qb * 32) * 1024;
#pragma unroll
  for (int m = 0; m < 2; ++m)
#pragma unroll
    for (int r = 0; r < 4; ++r) {
      const int rl = m * 16 + g * 4 + r;
      float s = reds[0][rl] + reds[1][rl] + reds[2][rl] + reds[3][rl];
      float iv = 1.0f / s;
#pragma unroll
      for (int pt = 0; pt < 16; ++pt) {
        const int col = (pt >> 3) * 512 + w * 128 + (pt & 7) * 16 + fr;
        float p = acc[m][pt][r] * iv;
        acc[m][pt][r] = p;
        sim[sim_base + (size_t)rl * 1024 + col] = p;
      }
    }

  // ---- Phase 5b/6: two 512-col chunks: stash P in LDS (swizzled), PV-accumulate ----
  f32x4 oacc[2][2] = {};
  const int d0 = w * 32;
#pragma unroll
  for (int cb = 0; cb < 2; ++cb) {
#pragma unroll
    for (int m = 0; m < 2; ++m)
#pragma unroll
      for (int r = 0; r < 4; ++r) {
        const int rl = m * 16 + g * 4 + r;
        const int swz = (rl & 15) << 3;  // element XOR (16B granularity)
#pragma unroll
        for (int p8 = 0; p8 < 8; ++p8) {
          const int colc = w * 128 + p8 * 16 + fr;   // col within chunk
          Pl[rl * 512 + (colc ^ swz)] = f2bf(acc[m][cb * 8 + p8][r]);
        }
      }
    __syncthreads();
#pragma unroll
    for (int ksl = 0; ksl < 16; ++ksl) {
      short8 pa[2], vb2[2];
#pragma unroll
      for (int m = 0; m < 2; ++m) {
        const int prow = m * 16 + fr;
        pa[m] = *(const short8*)&Pl[prow * 512 + ((ksl * 32 + ko) ^ ((prow & 15) << 3))];
      }
#pragma unroll
      for (int dt = 0; dt < 2; ++dt)
        vb2[dt] = *(const short8*)&Vp[(size_t)(d0 + dt * 16 + fr) * 1024 + cb * 512 + ksl * 32 + ko];
#pragma unroll
      for (int m = 0; m < 2; ++m)
#pragma unroll
        for (int dt = 0; dt < 2; ++dt)
          oacc[m][dt] = __builtin_amdgcn_mfma_f32_16x16x32_bf16(pa[m], vb2[dt], oacc[m][dt], 0, 0, 0);
    }
    __syncthreads();
  }

#pragma unroll
  for (int m = 0; m < 2; ++m)
#pragma unroll
    for (int dt = 0; dt < 2; ++dt)
#pragma unroll
      for (int r = 0; r < 4; ++r) {
        const int q = qb * 32 + m * 16 + g * 4 + r;
        const int d = d0 + dt * 16 + fr;
        out[((size_t)b * 1024 + q) * 1024 + h * 128 + d] = oacc[m][dt][r];
      }
}

extern "C" void kernel_launch(void* const* d_in, const int* in_sizes, int n_in,
                              void* d_out, int out_size, void* d_ws, size_t ws_size,
                              hipStream_t stream) {
  (void)in_sizes; (void)n_in; (void)out_size; (void)ws_size;
  const float* query = (const float*)d_in[0];
  const float* keys  = (const float*)d_in[1];
  const int*   mask  = (const int*)d_in[2];
  const float* rel   = (const float*)d_in[3];
  const float* Wq    = (const float*)d_in[4];
  const float* Wk    = (const float*)d_in[5];
  const float* Wv    = (const float*)d_in[6];

  float* out = (float*)d_out;                       // (B,Lq,D) = 8M floats
  float* sim = out + (size_t)8 * 1024 * 1024;       // (H*B,Lq,Lk) = 64M floats

  const size_t NE = (size_t)8 * 8 * 1024 * 128;     // 8.39M bf16 elems per buffer
  u16* Qb = (u16*)d_ws;                             // ws usage: 64 MB total
  u16* Kb = Qb + NE;
  u16* Vb = Kb + NE;
  u16* Vt = Vb + NE;

  qkv_gemm<<<dim3(64, 8, 3), TB, 0, stream>>>(query, keys, Wq, Wk, Wv, Qb, Kb, Vb);
  vtrans<<<dim3(32, 4, 64), TB, 0, stream>>>(Vb, Vt);
  fused_attn<<<dim3(2048), TB, 0, stream>>>(Qb, Kb, Vt, mask, rel, sim, out);
}

// Round 7
// 398.850 us; speedup vs baseline: 1.2080x; 1.0969x over previous
//
#include <hip/hip_runtime.h>

// Problem: B=8, Lq=Lk=1024, D=1024, H=8, dh=128.
// out0: (B,Lq,D) fp32 ; out1: similarity (H*B, Lq, Lk) fp32 (concatenated in d_out).
// Pipeline: [qkv proj bf16] -> [V transpose] -> [fused logits+softmax+PV]
// fused_attn = round-3 structure (242us, VGPR 128) + XCD swizzle + NT hints.

#define TB 256
#define LDST 56  // LDS row stride (elems) for 32-wide bf16 tiles

typedef __attribute__((ext_vector_type(8))) short short8;
typedef __attribute__((ext_vector_type(4))) float f32x4;
typedef unsigned short u16;

__device__ __forceinline__ u16 f2bf(float f) {
  union { float f; unsigned u; } v; v.f = f;
  unsigned r = v.u + 0x7fffu + ((v.u >> 16) & 1u);  // round-to-nearest-even
  return (u16)(r >> 16);
}

// ---------------- Kernel 1: QKV projections  y = x @ W^T  (NT GEMM, fp32 in, bf16 out) ----------------
__global__ __launch_bounds__(TB) void qkv_gemm(
    const float* __restrict__ query, const float* __restrict__ keys,
    const float* __restrict__ Wq, const float* __restrict__ Wk, const float* __restrict__ Wv,
    u16* __restrict__ Qb, u16* __restrict__ Kb, u16* __restrict__ Vb) {
  __shared__ u16 As[128 * LDST];
  __shared__ u16 Bs[128 * LDST];
  const int z = blockIdx.z;
  const float* __restrict__ x = (z == 0) ? query : keys;
  const float* __restrict__ W = (z == 0) ? Wq : (z == 1) ? Wk : Wv;
  u16* __restrict__ dst = (z == 0) ? Qb : (z == 1) ? Kb : Vb;

  const int t = threadIdx.x;
  const int lane = t & 63, wid = t >> 6;
  const int wr = wid >> 1, wc = wid & 1;
  const int fr = lane & 15, ko = (lane >> 4) * 8;
  const int m0 = blockIdx.x * 128, n0 = blockIdx.y * 128;

  f32x4 acc[4][4] = {};

  for (int k0 = 0; k0 < 1024; k0 += 32) {
#pragma unroll
    for (int it = 0; it < 4; ++it) {
      int j = it * 256 + t;
      int row = j >> 3, c4 = (j & 7) * 4;
      float4 va = *(const float4*)&x[(size_t)(m0 + row) * 1024 + k0 + c4];
      float4 vb = *(const float4*)&W[(size_t)(n0 + row) * 1024 + k0 + c4];
      *(ushort4*)&As[row * LDST + c4] = make_ushort4(f2bf(va.x), f2bf(va.y), f2bf(va.z), f2bf(va.w));
      *(ushort4*)&Bs[row * LDST + c4] = make_ushort4(f2bf(vb.x), f2bf(vb.y), f2bf(vb.z), f2bf(vb.w));
    }
    __syncthreads();
    short8 a[4], bfrag[4];
#pragma unroll
    for (int i = 0; i < 4; ++i) a[i] = *(const short8*)&As[(wr * 64 + i * 16 + fr) * LDST + ko];
#pragma unroll
    for (int j = 0; j < 4; ++j) bfrag[j] = *(const short8*)&Bs[(wc * 64 + j * 16 + fr) * LDST + ko];
#pragma unroll
    for (int i = 0; i < 4; ++i)
#pragma unroll
      for (int j = 0; j < 4; ++j)
        acc[i][j] = __builtin_amdgcn_mfma_f32_16x16x32_bf16(a[i], bfrag[j], acc[i][j], 0, 0, 0);
    __syncthreads();
  }

  const int h = blockIdx.y;
#pragma unroll
  for (int i = 0; i < 4; ++i)
#pragma unroll
    for (int j = 0; j < 4; ++j)
#pragma unroll
      for (int r = 0; r < 4; ++r) {
        int m = m0 + wr * 64 + i * 16 + (lane >> 4) * 4 + r;
        int d = wc * 64 + j * 16 + fr;
        int b_ = m >> 10, q = m & 1023;
        dst[(((size_t)(b_ * 8 + h)) * 1024 + q) * 128 + d] = f2bf(acc[i][j][r]);
      }
}

// ---------------- Kernel 2: V transpose  (b,h,k,d) -> (b,h,d,k) ----------------
__global__ __launch_bounds__(TB) void vtrans(const u16* __restrict__ Vb, u16* __restrict__ Vt) {
  __shared__ u16 tile[32][33];
  const int bh = blockIdx.z;
  const u16* __restrict__ src = Vb + (size_t)bh * 1024 * 128;
  u16* __restrict__ dst = Vt + (size_t)bh * 128 * 1024;
  const int k0 = blockIdx.x * 32, d0 = blockIdx.y * 32;
  const int t = threadIdx.x;
#pragma unroll
  for (int i = 0; i < 4; ++i) {
    int j = i * 256 + t;
    int r = j >> 5, c = j & 31;
    tile[r][c] = src[(size_t)(k0 + r) * 128 + d0 + c];
  }
  __syncthreads();
#pragma unroll
  for (int i = 0; i < 4; ++i) {
    int j = i * 256 + t;
    int r = j >> 5, c = j & 31;
    dst[(size_t)(d0 + r) * 1024 + k0 + c] = tile[c][r];
  }
}

// ---------------- Kernel 3: fused logits + softmax + PV (r3 structure) ----------------
// Block = (qb: 32 q-rows, bh). 4 waves; wave w owns columns [w*256, w*256+256).
// S row (1024) held in registers: acc[2][16] f32x4 per lane; acc dies fully at
// phase 5 (single-pass Pl write) -> natural VGPR ~128, no spill.
__global__ __launch_bounds__(TB) void fused_attn(
    const u16* __restrict__ Qb, const u16* __restrict__ Kb, const u16* __restrict__ Vt,
    const int* __restrict__ mask, const float* __restrict__ rel,
    float* __restrict__ sim, float* __restrict__ out) {
  __shared__ u16 Pl[32 * 1024];    // normalized P, bf16, XOR-swizzled (64 KB)
  __shared__ float redm[4][32];
  __shared__ float reds[4][32];

  // Bijective XCD swizzle: id&7 = XCD slot; all 32 q-blocks of a bh on one XCD.
  const int id = blockIdx.x;       // 2048 blocks
  const int jj = id >> 3;
  const int z = (id & 7) + 8 * (jj >> 5);  // bh index
  const int qb = jj & 31;
  const int h = z >> 3, b = z & 7;

  const int t = threadIdx.x;
  const int lane = t & 63, w = t >> 6;
  const int fr = lane & 15, g = lane >> 4;
  const int ko = g * 8;

  const size_t bh_off = (size_t)(b * 8 + h) * 1024 * 128;
  const u16* __restrict__ Qp = Qb + bh_off + (size_t)(qb * 32) * 128;
  const u16* __restrict__ Kp = Kb + bh_off;
  const u16* __restrict__ Vp = Vt + bh_off;   // (d,k) layout

  // ---- Phase 1: S = Q.K^T  (rows 32, cols 1024; wave handles 256 cols) ----
  short8 qf[2][4];
#pragma unroll
  for (int m = 0; m < 2; ++m)
#pragma unroll
    for (int ks = 0; ks < 4; ++ks)
      qf[m][ks] = *(const short8*)&Qp[(size_t)(m * 16 + fr) * 128 + ks * 32 + ko];

  f32x4 acc[2][16] = {};
#pragma unroll
  for (int pt = 0; pt < 16; ++pt) {
    const u16* kb = Kp + (size_t)(w * 256 + pt * 16 + fr) * 128 + ko;
#pragma unroll
    for (int ks = 0; ks < 4; ++ks) {
      short8 kf = *(const short8*)&kb[ks * 32];
      acc[0][pt] = __builtin_amdgcn_mfma_f32_16x16x32_bf16(qf[0][ks], kf, acc[0][pt], 0, 0, 0);
      acc[1][pt] = __builtin_amdgcn_mfma_f32_16x16x32_bf16(qf[1][ks], kf, acc[1][pt], 0, 0, 0);
    }
  }

  // ---- Phase 2: rel + mask, in-register (NT loads: lines touched exactly once) ----
  const float scale = 0.03125f;  // 1/sqrt(1024)
#pragma unroll
  for (int m = 0; m < 2; ++m)
#pragma unroll
    for (int r = 0; r < 4; ++r) {
      const int qrow = qb * 32 + m * 16 + g * 4 + r;
      const size_t rbase = ((size_t)b * 1024 + qrow) * 1024 + w * 256 + fr;
#pragma unroll
      for (int pt = 0; pt < 16; ++pt) {
        size_t idx = rbase + pt * 16;
        float rv = __builtin_nontemporal_load(&rel[idx]);
        int mv = __builtin_nontemporal_load(&mask[idx]);
        float v = (acc[m][pt][r] + rv) * scale;
        acc[m][pt][r] = (mv > 0) ? v : -1e9f;
      }
    }

  // ---- Phase 3: row max (local 16 -> shfl over 16-lane group -> LDS cross-wave) ----
  float mloc[2][4];
#pragma unroll
  for (int m = 0; m < 2; ++m)
#pragma unroll
    for (int r = 0; r < 4; ++r) {
      float mx = acc[m][0][r];
#pragma unroll
      for (int pt = 1; pt < 16; ++pt) mx = fmaxf(mx, acc[m][pt][r]);
      mx = fmaxf(mx, __shfl_xor(mx, 1));
      mx = fmaxf(mx, __shfl_xor(mx, 2));
      mx = fmaxf(mx, __shfl_xor(mx, 4));
      mx = fmaxf(mx, __shfl_xor(mx, 8));
      mloc[m][r] = mx;
    }
  if (fr == 0) {
#pragma unroll
    for (int m = 0; m < 2; ++m)
#pragma unroll
      for (int r = 0; r < 4; ++r) redm[w][m * 16 + g * 4 + r] = mloc[m][r];
  }
  __syncthreads();

  // ---- Phase 4: exp + row sum ----
  float sv[2][4];
#pragma unroll
  for (int m = 0; m < 2; ++m)
#pragma unroll
    for (int r = 0; r < 4; ++r) {
      const int rl = m * 16 + g * 4 + r;
      float mx = fmaxf(fmaxf(redm[0][rl], redm[1][rl]), fmaxf(redm[2][rl], redm[3][rl]));
      float s = 0.f;
#pragma unroll
      for (int pt = 0; pt < 16; ++pt) {
        float e = __expf(acc[m][pt][r] - mx);
        acc[m][pt][r] = e;
        s += e;
      }
      s += __shfl_xor(s, 1);
      s += __shfl_xor(s, 2);
      s += __shfl_xor(s, 4);
      s += __shfl_xor(s, 8);
      sv[m][r] = s;
    }
  if (fr == 0) {
#pragma unroll
    for (int m = 0; m < 2; ++m)
#pragma unroll
      for (int r = 0; r < 4; ++r) reds[w][m * 16 + g * 4 + r] = sv[m][r];
  }
  __syncthreads();

  // ---- Phase 5: normalize; write sim (fp32, NT) + P (bf16, swizzled LDS); acc dies here ----
  const size_t sim_base = ((size_t)(h * 8 + b) * 1024 + qb * 32) * 1024;
#pragma unroll
  for (int m = 0; m < 2; ++m)
#pragma unroll
    for (int r = 0; r < 4; ++r) {
      const int rl = m * 16 + g * 4 + r;
      float s = reds[0][rl] + reds[1][rl] + reds[2][rl] + reds[3][rl];
      float iv = 1.0f / s;
      const int swz = (rl & 15) << 3;  // element XOR (16B granularity)
#pragma unroll
      for (int pt = 0; pt < 16; ++pt) {
        const int col = w * 256 + pt * 16 + fr;
        float p = acc[m][pt][r] * iv;
        __builtin_nontemporal_store(p, &sim[sim_base + (size_t)rl * 1024 + col]);
        Pl[rl * 1024 + (col ^ swz)] = f2bf(p);
      }
    }
  __syncthreads();

  // ---- Phase 6: out(32x128) = P(32x1024) @ V^T  (Vt is (d,k), k-contiguous) ----
  // wave w -> d-tiles {2w, 2w+1}, m-tiles {0,1}
  f32x4 oacc[2][2] = {};
  const int d0 = w * 32;
#pragma unroll
  for (int ksl = 0; ksl < 32; ++ksl) {
    short8 pa[2], vb2[2];
#pragma unroll
    for (int m = 0; m < 2; ++m) {
      const int prow = m * 16 + fr;
      pa[m] = *(const short8*)&Pl[prow * 1024 + ((ksl * 32 + ko) ^ ((prow & 15) << 3))];
    }
#pragma unroll
    for (int dt = 0; dt < 2; ++dt)
      vb2[dt] = *(const short8*)&Vp[(size_t)(d0 + dt * 16 + fr) * 1024 + ksl * 32 + ko];
#pragma unroll
    for (int m = 0; m < 2; ++m)
#pragma unroll
      for (int dt = 0; dt < 2; ++dt)
        oacc[m][dt] = __builtin_amdgcn_mfma_f32_16x16x32_bf16(pa[m], vb2[dt], oacc[m][dt], 0, 0, 0);
  }

#pragma unroll
  for (int m = 0; m < 2; ++m)
#pragma unroll
    for (int dt = 0; dt < 2; ++dt)
#pragma unroll
      for (int r = 0; r < 4; ++r) {
        const int q = qb * 32 + m * 16 + g * 4 + r;
        const int d = d0 + dt * 16 + fr;
        __builtin_nontemporal_store(oacc[m][dt][r],
                                    &out[((size_t)b * 1024 + q) * 1024 + h * 128 + d]);
      }
}

extern "C" void kernel_launch(void* const* d_in, const int* in_sizes, int n_in,
                              void* d_out, int out_size, void* d_ws, size_t ws_size,
                              hipStream_t stream) {
  (void)in_sizes; (void)n_in; (void)out_size; (void)ws_size;
  const float* query = (const float*)d_in[0];
  const float* keys  = (const float*)d_in[1];
  const int*   mask  = (const int*)d_in[2];
  const float* rel   = (const float*)d_in[3];
  const float* Wq    = (const float*)d_in[4];
  const float* Wk    = (const float*)d_in[5];
  const float* Wv    = (const float*)d_in[6];

  float* out = (float*)d_out;                       // (B,Lq,D) = 8M floats
  float* sim = out + (size_t)8 * 1024 * 1024;       // (H*B,Lq,Lk) = 64M floats

  const size_t NE = (size_t)8 * 8 * 1024 * 128;     // 8.39M bf16 elems per buffer
  u16* Qb = (u16*)d_ws;                             // ws usage: 64 MB total
  u16* Kb = Qb + NE;
  u16* Vb = Kb + NE;
  u16* Vt = Vb + NE;

  qkv_gemm<<<dim3(64, 8, 3), TB, 0, stream>>>(query, keys, Wq, Wk, Wv, Qb, Kb, Vb);
  vtrans<<<dim3(32, 4, 64), TB, 0, stream>>>(Vb, Vt);
  fused_attn<<<dim3(2048), TB, 0, stream>>>(Qb, Kb, Vt, mask, rel, sim, out);
}